// Round 1
// baseline (113940.515 us; speedup 1.0000x reference)
//
#include <hip/hip_runtime.h>
#include <cstdint>

// ---------------------------------------------------------------------------
// HierarchicalGraphMemoryNetwork on MI355X — round 1 (correctness baseline)
//
// Structure:
//   - All LSTM input projections (x @ Wih^T + b) hoisted into parallel fp32
//     GEMMs ("Xp" buffers).
//   - Each LSTM scan = 1 persistent workgroup (1024 thr = 16 waves) on 1 CU.
//     Thread j owns gate-row j of Whh [1024][256] (f16): 96/128 weight dwords
//     in VGPRs, 32 streamed from a 128KB LDS tile. Recurrent GEMV done with
//     v_dot2_f32_f16 (fp32 accumulate), h broadcast via LDS, fp32 cell state.
//   - bilstm fwd/bwd run as 2 blocks of one kernel (concurrent CUs).
// ---------------------------------------------------------------------------

#define T_LEN 8192
#define IN_F  256
#define HID   256
#define GATE  1024
#define NREL  4
#define OUT_N 256

typedef _Float16 half2_t __attribute__((ext_vector_type(2)));

__device__ __forceinline__ float fdot2(uint32_t w, uint32_t h, float acc) {
#if __has_builtin(__builtin_amdgcn_fdot2)
  return __builtin_amdgcn_fdot2(__builtin_bit_cast(half2_t, w),
                                __builtin_bit_cast(half2_t, h), acc, false);
#else
  half2_t a = __builtin_bit_cast(half2_t, w), b = __builtin_bit_cast(half2_t, h);
  return acc + (float)a.x * (float)b.x + (float)a.y * (float)b.y;
#endif
}

__device__ __forceinline__ float fsig(float x) { return 1.f / (1.f + __expf(-x)); }
__device__ __forceinline__ float ftanh(float x) { return 2.f / (1.f + __expf(-2.f * x)) - 1.f; }

// -------------------------- fp32 -> f16 convert ----------------------------
__global__ void f2h_kernel(const float* __restrict__ in, _Float16* __restrict__ out, int n) {
  int i = blockIdx.x * blockDim.x + threadIdx.x;
  if (i < n) out[i] = (_Float16)in[i];
}

// ------------------------------- GEMM --------------------------------------
// C[M][N] = A[M][K] * W[N][K]^T (+ bias[N]) (+ addC[M][N]); 64x64 tile/block.
__global__ __launch_bounds__(256) void gemm_kernel(
    const float* __restrict__ A, int lda,
    const float* __restrict__ W, int ldw,
    const float* __restrict__ bias,
    const float* addC,
    float* C, int ldc, int M, int N, int K) {
  __shared__ float As[16][64];
  __shared__ float Bs[16][64];
  const int tid = threadIdx.x;
  const int tx = tid & 15, ty = tid >> 4;
  const int m0 = blockIdx.y * 64, n0 = blockIdx.x * 64;
  const int lr = tid >> 2;          // 0..63
  const int lc = (tid & 3) * 4;     // 0,4,8,12
  float acc[4][4] = {};
  for (int k0 = 0; k0 < K; k0 += 16) {
    float4 av = *(const float4*)&A[(size_t)(m0 + lr) * lda + k0 + lc];
    float4 wv = *(const float4*)&W[(size_t)(n0 + lr) * ldw + k0 + lc];
    As[lc + 0][lr] = av.x; As[lc + 1][lr] = av.y; As[lc + 2][lr] = av.z; As[lc + 3][lr] = av.w;
    Bs[lc + 0][lr] = wv.x; Bs[lc + 1][lr] = wv.y; Bs[lc + 2][lr] = wv.z; Bs[lc + 3][lr] = wv.w;
    __syncthreads();
#pragma unroll
    for (int k = 0; k < 16; ++k) {
      float a[4], b[4];
#pragma unroll
      for (int i = 0; i < 4; ++i) a[i] = As[k][ty * 4 + i];
#pragma unroll
      for (int j = 0; j < 4; ++j) b[j] = Bs[k][tx * 4 + j];
#pragma unroll
      for (int i = 0; i < 4; ++i)
#pragma unroll
        for (int j = 0; j < 4; ++j) acc[i][j] += a[i] * b[j];
    }
    __syncthreads();
  }
#pragma unroll
  for (int i = 0; i < 4; ++i) {
    int m = m0 + ty * 4 + i;
#pragma unroll
    for (int j = 0; j < 4; ++j) {
      int n = n0 + tx * 4 + j;
      float v = acc[i][j];
      if (bias) v += bias[n];
      if (addC) v += addC[(size_t)m * ldc + n];
      C[(size_t)m * ldc + n] = v;
    }
  }
}

// ------------------------------ gather -------------------------------------
// pair[t] = [nodes[e0[t]], nodes[e1[t]]]
__global__ void gather_kernel(const float* __restrict__ nodes,
                              const int* __restrict__ edges,
                              float* __restrict__ pair) {
  int t = blockIdx.x;
  int c = threadIdx.x;              // 0..511
  int e = edges[t * 2 + (c >> 8)];
  pair[(size_t)t * 512 + c] = nodes[(size_t)e * 256 + (c & 255)];
}

// ------------------------------ LSTM scan ----------------------------------
// One block per scan direction. Thread j = gate-row j (z layout [i,f,g,o]).
__global__ __launch_bounds__(1024) void lstm_scan_kernel(
    const float* Xp0, const uint32_t* W0, float* out0, int rev0,
    const float* Xp1, const uint32_t* W1, float* out1, int rev1,
    int hstride, int T) {
  const float* Xp; const uint32_t* W; float* out; int rev;
  if (blockIdx.x == 0) { Xp = Xp0; W = W0; out = out0; rev = rev0; }
  else                 { Xp = Xp1; W = W1; out = out1; rev = rev1; }

  const int j = threadIdx.x;                       // 0..1023
  __shared__ uint4 w_lds[8][1024];                 // 128 KiB: weight dwords 96..127
  __shared__ float z_lds[1024];
  __shared__ uint32_t h_lds[128];                  // 256 f16

  const uint4* wrow = (const uint4*)(W + (size_t)j * 128);
  uint4 wr[24];
#pragma unroll
  for (int q = 0; q < 24; ++q) wr[q] = wrow[q];
#pragma unroll
  for (int q = 0; q < 8; ++q) w_lds[q][j] = wrow[24 + q];
  if (j < 128) h_lds[j] = 0u;
  float c = 0.f;
  __syncthreads();

  float xp_next = Xp[(size_t)(rev ? (T - 1) : 0) * GATE + j];
  for (int s = 0; s < T; ++s) {
    const int t = rev ? (T - 1 - s) : s;
    float s0 = xp_next, s1 = 0.f, s2 = 0.f, s3 = 0.f;
    if (s + 1 < T) xp_next = Xp[(size_t)(rev ? (t - 1) : (t + 1)) * GATE + j];

    const uint4* hq = (const uint4*)h_lds;
#pragma unroll
    for (int q = 0; q < 24; ++q) {
      uint4 hv = hq[q]; uint4 wv = wr[q];
      s0 = fdot2(wv.x, hv.x, s0);
      s1 = fdot2(wv.y, hv.y, s1);
      s2 = fdot2(wv.z, hv.z, s2);
      s3 = fdot2(wv.w, hv.w, s3);
    }
#pragma unroll
    for (int q = 0; q < 8; ++q) {
      uint4 hv = hq[24 + q]; uint4 wv = w_lds[q][j];
      s0 = fdot2(wv.x, hv.x, s0);
      s1 = fdot2(wv.y, hv.y, s1);
      s2 = fdot2(wv.z, hv.z, s2);
      s3 = fdot2(wv.w, hv.w, s3);
    }
    z_lds[j] = (s0 + s1) + (s2 + s3);
    __syncthreads();

    if (j < HID) {
      float zi = z_lds[j], zf = z_lds[j + 256], zg = z_lds[j + 512], zo = z_lds[j + 768];
      float ig = fsig(zi), fg = fsig(zf), gg = ftanh(zg), og = fsig(zo);
      c = fg * c + ig * gg;
      float h = og * ftanh(c);
      out[(size_t)t * hstride + j] = h;
      ((_Float16*)h_lds)[j] = (_Float16)h;
    }
    __syncthreads();
  }
}

// ---------------------------------------------------------------------------
extern "C" void kernel_launch(void* const* d_in, const int* in_sizes, int n_in,
                              void* d_out, int out_size, void* d_ws, size_t ws_size,
                              hipStream_t stream) {
  (void)in_sizes; (void)n_in; (void)out_size; (void)ws_size;
  const float* inputs = (const float*)d_in[0];
  const int*   edges  = (const int*)d_in[1];
  const float* memory = (const float*)d_in[2];
  const float* Wl_ih  = (const float*)d_in[3];
  const float* Wl_hh  = (const float*)d_in[4];
  const float* bl     = (const float*)d_in[5];
  const float* Wh_ih  = (const float*)d_in[6];
  const float* Wh_hh  = (const float*)d_in[7];
  const float* bh     = (const float*)d_in[8];
  const float* Win    = (const float*)d_in[9];
  const float* bin_   = (const float*)d_in[10];
  const float* We     = (const float*)d_in[11];
  const float* be     = (const float*)d_in[12];
  const float* Wn_ih  = (const float*)d_in[13];
  const float* Wn_hh  = (const float*)d_in[14];
  const float* bn     = (const float*)d_in[15];
  const float* Wmem   = (const float*)d_in[16];
  const float* bmem   = (const float*)d_in[17];
  const float* Wc_ih  = (const float*)d_in[18];
  const float* Wc_hh  = (const float*)d_in[19];
  const float* bc     = (const float*)d_in[20];
  const float* Wout   = (const float*)d_in[21];
  const float* bout   = (const float*)d_in[22];

  float* out_ptr = (float*)d_out;                       // [T][256]
  float* memvec  = out_ptr + (size_t)T_LEN * OUT_N;     // [T][256]

  // ---- workspace carve ----
  char* base = (char*)d_ws;
  size_t off = 0;
  auto carve = [&](size_t nbytes) -> void* {
    void* p = base + off; off += (nbytes + 255) & ~(size_t)255; return p;
  };
  float* XpA    = (float*)carve((size_t)T_LEN * GATE * 4);
  float* XpB    = (float*)carve((size_t)T_LEN * GATE * 4);
  float* XpC    = (float*)carve((size_t)T_LEN * GATE * 4);
  float* XpN    = (float*)carve((size_t)T_LEN * GATE * 4);
  float* lower  = (float*)carve((size_t)T_LEN * 512 * 4);
  float* higher = (float*)carve((size_t)T_LEN * 512 * 4);
  float* nodesA = (float*)carve((size_t)T_LEN * 256 * 4);
  float* nodesB = (float*)carve((size_t)T_LEN * 256 * 4);
  float* pairb  = (float*)carve((size_t)T_LEN * 512 * 4);
  float* ehb    = (float*)carve((size_t)T_LEN * 256 * 4);
  float* ctrlh  = (float*)carve((size_t)T_LEN * 256 * 4);
  uint32_t* Wl16 = (uint32_t*)carve((size_t)2 * GATE * HID * 2);
  uint32_t* Wh16 = (uint32_t*)carve((size_t)2 * GATE * HID * 2);
  uint32_t* Wn16 = (uint32_t*)carve((size_t)4 * GATE * HID * 2);
  uint32_t* Wc16 = (uint32_t*)carve((size_t)1 * GATE * HID * 2);
  const size_t WMAT = (size_t)GATE * HID / 2;   // uints per [1024][256] f16 matrix

  // ---- weight conversions ----
  auto f2h = [&](const float* src, uint32_t* dst, int n) {
    f2h_kernel<<<(n + 255) / 256, 256, 0, stream>>>(src, (_Float16*)dst, n);
  };
  f2h(Wl_hh, Wl16, 2 * GATE * HID);
  f2h(Wh_hh, Wh16, 2 * GATE * HID);
  f2h(Wn_hh, Wn16, 4 * GATE * HID);
  f2h(Wc_hh, Wc16, 1 * GATE * HID);

  auto gemm = [&](float* C, int ldc, const float* A, int lda,
                  const float* W, int ldw, const float* bias, const float* addC,
                  int M, int N, int K) {
    dim3 g(N / 64, M / 64);
    gemm_kernel<<<g, 256, 0, stream>>>(A, lda, W, ldw, bias, addC, C, ldc, M, N, K);
  };
  auto scan = [&](const float* Xq0, const uint32_t* Wq0, float* o0, int r0,
                  const float* Xq1, const uint32_t* Wq1, float* o1, int r1,
                  int hstride, int nblk) {
    lstm_scan_kernel<<<nblk, 1024, 0, stream>>>(Xq0, Wq0, o0, r0, Xq1, Wq1, o1, r1, hstride, T_LEN);
  };

  // ---- lower bilstm ----
  gemm(XpA, GATE, inputs, IN_F, Wl_ih,                 IN_F, bl,        nullptr, T_LEN, GATE, IN_F);
  gemm(XpB, GATE, inputs, IN_F, Wl_ih + GATE * IN_F,   IN_F, bl + GATE, nullptr, T_LEN, GATE, IN_F);
  scan(XpA, Wl16, lower, 0, XpB, Wl16 + WMAT, lower + 256, 1, 512, 2);

  // ---- higher bilstm ----
  gemm(XpA, GATE, lower, 512, Wh_ih,               512, bh,        nullptr, T_LEN, GATE, 512);
  gemm(XpB, GATE, lower, 512, Wh_ih + GATE * 512,  512, bh + GATE, nullptr, T_LEN, GATE, 512);
  scan(XpA, Wh16, higher, 0, XpB, Wh16 + WMAT, higher + 256, 1, 512, 2);

  // ---- ctrl Xp = inputs part + memory part + higher part + bc ----
  gemm(XpC, GATE, inputs, IN_F, Wc_ih,        896, bc,      nullptr, T_LEN, GATE, IN_F);
  gemm(XpC, GATE, memory, 128,  Wc_ih + 768,  896, nullptr, XpC,     T_LEN, GATE, 128);
  gemm(XpC, GATE, higher, 512,  Wc_ih + 256,  896, nullptr, XpC,     T_LEN, GATE, 512);

  // ---- nodes init ----
  gemm(nodesA, 256, inputs, IN_F, Win, IN_F, bin_, nullptr, T_LEN, 256, IN_F);

  // ---- relation loop ----
  float* ncur = nodesA;
  float* nnext = nodesB;
  for (int r = 0; r < NREL; ++r) {
    gather_kernel<<<T_LEN, 512, 0, stream>>>(ncur, edges, pairb);
    gemm(ehb, 256, pairb, 512, We + (size_t)r * HID * 512, 512, be + r * HID, nullptr, T_LEN, 256, 512);
    gemm(XpN, GATE, inputs, IN_F, Wn_ih + (size_t)r * GATE * 512,       512, bn + r * GATE, nullptr, T_LEN, GATE, IN_F);
    gemm(XpN, GATE, ehb,    256,  Wn_ih + (size_t)r * GATE * 512 + 256, 512, nullptr,       XpN,     T_LEN, GATE, 256);
    scan(XpN, Wn16 + (size_t)r * WMAT, nnext, 0, XpN, Wn16 + (size_t)r * WMAT, nnext, 0, 256, 1);
    float* tmp = ncur; ncur = nnext; nnext = tmp;
  }

  // ---- memory vector (output 1) ----
  gemm(memvec, 256, ncur, 256, Wmem, HID, bmem, nullptr, T_LEN, 256, HID);

  // ---- ctrl scan + output projection (output 0) ----
  scan(XpC, Wc16, ctrlh, 0, XpC, Wc16, ctrlh, 0, 256, 1);
  gemm(out_ptr, 256, ctrlh, 256, Wout, HID, bout, nullptr, T_LEN, 256, HID);
}

// Round 2
// 64934.015 us; speedup vs baseline: 1.7547x; 1.7547x over previous
//
#include <hip/hip_runtime.h>
#include <cstdint>

// ---------------------------------------------------------------------------
// HierarchicalGraphMemoryNetwork on MI355X — round 2
//
// Changes vs round 1:
//  - Scan kernel: 512 threads (2 waves/SIMD -> 256 VGPR cap), each thread owns
//    2 gate rows; 96 weight-dwords/row in VGPR (192 regs, no spill), 32/row in
//    a 128 KiB LDS tile. Round 1 spilled (VGPR_Count=64) and was ~10x slow.
//  - Slot-merged schedule: independent scans share one launch (multi-block):
//    [lower fwd/bwd + node0], [higher fwd/bwd + node1], [node2 + ctrl], [node3].
// ---------------------------------------------------------------------------

#define T_LEN 8192
#define IN_F  256
#define HID   256
#define GATE  1024
#define NREL  4
#define OUT_N 256

typedef _Float16 half2_t __attribute__((ext_vector_type(2)));

__device__ __forceinline__ float fdot2(uint32_t w, uint32_t h, float acc) {
#if __has_builtin(__builtin_amdgcn_fdot2)
  return __builtin_amdgcn_fdot2(__builtin_bit_cast(half2_t, w),
                                __builtin_bit_cast(half2_t, h), acc, false);
#else
  asm("v_dot2_f32_f16 %0, %1, %2, %0" : "+v"(acc) : "v"(w), "v"(h));
  return acc;
#endif
}

__device__ __forceinline__ float fsig(float x) { return 1.f / (1.f + __expf(-x)); }
__device__ __forceinline__ float ftanh(float x) { return 2.f / (1.f + __expf(-2.f * x)) - 1.f; }

// -------------------------- fp32 -> f16 convert ----------------------------
__global__ void f2h_kernel(const float* __restrict__ in, _Float16* __restrict__ out, int n) {
  int i = blockIdx.x * blockDim.x + threadIdx.x;
  if (i < n) out[i] = (_Float16)in[i];
}

// ------------------------------- GEMM --------------------------------------
// C[M][N] = A[M][K] * W[N][K]^T (+ bias[N]) (+ addC[M][N]); 64x64 tile/block.
__global__ __launch_bounds__(256) void gemm_kernel(
    const float* __restrict__ A, int lda,
    const float* __restrict__ W, int ldw,
    const float* __restrict__ bias,
    const float* addC,
    float* C, int ldc, int M, int N, int K) {
  __shared__ float As[16][64];
  __shared__ float Bs[16][64];
  const int tid = threadIdx.x;
  const int tx = tid & 15, ty = tid >> 4;
  const int m0 = blockIdx.y * 64, n0 = blockIdx.x * 64;
  const int lr = tid >> 2;          // 0..63
  const int lc = (tid & 3) * 4;     // 0,4,8,12
  float acc[4][4] = {};
  for (int k0 = 0; k0 < K; k0 += 16) {
    float4 av = *(const float4*)&A[(size_t)(m0 + lr) * lda + k0 + lc];
    float4 wv = *(const float4*)&W[(size_t)(n0 + lr) * ldw + k0 + lc];
    As[lc + 0][lr] = av.x; As[lc + 1][lr] = av.y; As[lc + 2][lr] = av.z; As[lc + 3][lr] = av.w;
    Bs[lc + 0][lr] = wv.x; Bs[lc + 1][lr] = wv.y; Bs[lc + 2][lr] = wv.z; Bs[lc + 3][lr] = wv.w;
    __syncthreads();
#pragma unroll
    for (int k = 0; k < 16; ++k) {
      float a[4], b[4];
#pragma unroll
      for (int i = 0; i < 4; ++i) a[i] = As[k][ty * 4 + i];
#pragma unroll
      for (int j = 0; j < 4; ++j) b[j] = Bs[k][tx * 4 + j];
#pragma unroll
      for (int i = 0; i < 4; ++i)
#pragma unroll
        for (int j = 0; j < 4; ++j) acc[i][j] += a[i] * b[j];
    }
    __syncthreads();
  }
#pragma unroll
  for (int i = 0; i < 4; ++i) {
    int m = m0 + ty * 4 + i;
#pragma unroll
    for (int j = 0; j < 4; ++j) {
      int n = n0 + tx * 4 + j;
      float v = acc[i][j];
      if (bias) v += bias[n];
      if (addC) v += addC[(size_t)m * ldc + n];
      C[(size_t)m * ldc + n] = v;
    }
  }
}

// ------------------------------ gather -------------------------------------
__global__ void gather_kernel(const float* __restrict__ nodes,
                              const int* __restrict__ edges,
                              float* __restrict__ pair) {
  int t = blockIdx.x;
  int c = threadIdx.x;              // 0..511
  int e = edges[t * 2 + (c >> 8)];
  pair[(size_t)t * 512 + c] = nodes[(size_t)e * 256 + (c & 255)];
}

// ------------------------------ LSTM scan ----------------------------------
// 512 threads. Thread j owns gate rows j and j+512 of Whh [1024][256] f16.
// Per row: dwords 0..95 (k=0..191) in VGPR, dwords 96..127 (k=192..255) in LDS.
struct ScanDesc {
  const float* Xp;        // [T][1024] fp32 input projection (incl. bias)
  const uint32_t* W;      // [1024][128] dwords of f16 Whh
  float* out;             // h output
  int rev;                // reverse scan
  int hstride;            // out row stride
};

__global__ __launch_bounds__(512, 2) void lstm_scan2(
    ScanDesc d0, ScanDesc d1, ScanDesc d2, int T) {
  ScanDesc d;
  if (blockIdx.x == 0) d = d0;
  else if (blockIdx.x == 1) d = d1;
  else d = d2;
  const float* __restrict__ Xp = d.Xp;
  const uint32_t* __restrict__ W = d.W;
  float* __restrict__ out = d.out;
  const int rev = d.rev, hstride = d.hstride;

  const int j = threadIdx.x;                 // 0..511
  __shared__ uint4 w_lds[2][8][512];         // 128 KiB (dwords 96..127 of both rows)
  __shared__ float z_lds[1024];
  __shared__ uint32_t h_lds[128];            // 256 f16

  const uint4* wrow0 = (const uint4*)(W + (size_t)j * 128);
  const uint4* wrow1 = (const uint4*)(W + (size_t)(j + 512) * 128);
  uint4 w0[24], w1[24];
#pragma unroll
  for (int q = 0; q < 24; ++q) w0[q] = wrow0[q];
#pragma unroll
  for (int q = 0; q < 24; ++q) w1[q] = wrow1[q];
#pragma unroll
  for (int q = 0; q < 8; ++q) w_lds[0][q][j] = wrow0[24 + q];
#pragma unroll
  for (int q = 0; q < 8; ++q) w_lds[1][q][j] = wrow1[24 + q];
  if (j < 128) h_lds[j] = 0u;
  float c = 0.f;
  __syncthreads();

  int t0 = rev ? (T - 1) : 0;
  float xp0 = Xp[(size_t)t0 * GATE + j];
  float xp1 = Xp[(size_t)t0 * GATE + j + 512];

  for (int s = 0; s < T; ++s) {
    const int t = rev ? (T - 1 - s) : s;
    float a0 = xp0, a1 = 0.f, a2 = 0.f, a3 = 0.f;     // row j accumulators
    float b0 = xp1, b1 = 0.f, b2 = 0.f, b3 = 0.f;     // row j+512 accumulators
    if (s + 1 < T) {
      const int tn = rev ? (t - 1) : (t + 1);
      xp0 = Xp[(size_t)tn * GATE + j];
      xp1 = Xp[(size_t)tn * GATE + j + 512];
    }

    const uint4* hq = (const uint4*)h_lds;
#pragma unroll
    for (int q = 0; q < 24; ++q) {
      uint4 hv = hq[q];
      uint4 wa = w0[q], wb = w1[q];
      a0 = fdot2(wa.x, hv.x, a0); b0 = fdot2(wb.x, hv.x, b0);
      a1 = fdot2(wa.y, hv.y, a1); b1 = fdot2(wb.y, hv.y, b1);
      a2 = fdot2(wa.z, hv.z, a2); b2 = fdot2(wb.z, hv.z, b2);
      a3 = fdot2(wa.w, hv.w, a3); b3 = fdot2(wb.w, hv.w, b3);
    }
#pragma unroll
    for (int q = 0; q < 8; ++q) {
      uint4 hv = hq[24 + q];
      uint4 wa = w_lds[0][q][j], wb = w_lds[1][q][j];
      a0 = fdot2(wa.x, hv.x, a0); b0 = fdot2(wb.x, hv.x, b0);
      a1 = fdot2(wa.y, hv.y, a1); b1 = fdot2(wb.y, hv.y, b1);
      a2 = fdot2(wa.z, hv.z, a2); b2 = fdot2(wb.z, hv.z, b2);
      a3 = fdot2(wa.w, hv.w, a3); b3 = fdot2(wb.w, hv.w, b3);
    }
    z_lds[j] = (a0 + a1) + (a2 + a3);
    z_lds[j + 512] = (b0 + b1) + (b2 + b3);
    __syncthreads();

    if (j < HID) {
      float zi = z_lds[j], zf = z_lds[j + 256], zg = z_lds[j + 512], zo = z_lds[j + 768];
      float ig = fsig(zi), fg = fsig(zf), gg = ftanh(zg), og = fsig(zo);
      c = fg * c + ig * gg;
      float h = og * ftanh(c);
      out[(size_t)t * hstride + j] = h;
      ((_Float16*)h_lds)[j] = (_Float16)h;
    }
    __syncthreads();
  }
}

// ---------------------------------------------------------------------------
extern "C" void kernel_launch(void* const* d_in, const int* in_sizes, int n_in,
                              void* d_out, int out_size, void* d_ws, size_t ws_size,
                              hipStream_t stream) {
  (void)in_sizes; (void)n_in; (void)out_size; (void)ws_size;
  const float* inputs = (const float*)d_in[0];
  const int*   edges  = (const int*)d_in[1];
  const float* memory = (const float*)d_in[2];
  const float* Wl_ih  = (const float*)d_in[3];
  const float* Wl_hh  = (const float*)d_in[4];
  const float* bl     = (const float*)d_in[5];
  const float* Wh_ih  = (const float*)d_in[6];
  const float* Wh_hh  = (const float*)d_in[7];
  const float* bh     = (const float*)d_in[8];
  const float* Win    = (const float*)d_in[9];
  const float* bin_   = (const float*)d_in[10];
  const float* We     = (const float*)d_in[11];
  const float* be     = (const float*)d_in[12];
  const float* Wn_ih  = (const float*)d_in[13];
  const float* Wn_hh  = (const float*)d_in[14];
  const float* bn     = (const float*)d_in[15];
  const float* Wmem   = (const float*)d_in[16];
  const float* bmem   = (const float*)d_in[17];
  const float* Wc_ih  = (const float*)d_in[18];
  const float* Wc_hh  = (const float*)d_in[19];
  const float* bc     = (const float*)d_in[20];
  const float* Wout   = (const float*)d_in[21];
  const float* bout   = (const float*)d_in[22];

  float* out_ptr = (float*)d_out;                       // [T][256]
  float* memvec  = out_ptr + (size_t)T_LEN * OUT_N;     // [T][256]

  // ---- workspace carve ----
  char* base = (char*)d_ws;
  size_t off = 0;
  auto carve = [&](size_t nbytes) -> void* {
    void* p = base + off; off += (nbytes + 255) & ~(size_t)255; return p;
  };
  float* XpA    = (float*)carve((size_t)T_LEN * GATE * 4);
  float* XpB    = (float*)carve((size_t)T_LEN * GATE * 4);
  float* XpC    = (float*)carve((size_t)T_LEN * GATE * 4);
  float* XpN    = (float*)carve((size_t)T_LEN * GATE * 4);
  float* lower  = (float*)carve((size_t)T_LEN * 512 * 4);
  float* higher = (float*)carve((size_t)T_LEN * 512 * 4);
  float* nodesA = (float*)carve((size_t)T_LEN * 256 * 4);
  float* nodesB = (float*)carve((size_t)T_LEN * 256 * 4);
  float* pairb  = (float*)carve((size_t)T_LEN * 512 * 4);
  float* ehb    = (float*)carve((size_t)T_LEN * 256 * 4);
  float* ctrlh  = (float*)carve((size_t)T_LEN * 256 * 4);
  uint32_t* Wl16 = (uint32_t*)carve((size_t)2 * GATE * HID * 2);
  uint32_t* Wh16 = (uint32_t*)carve((size_t)2 * GATE * HID * 2);
  uint32_t* Wn16 = (uint32_t*)carve((size_t)4 * GATE * HID * 2);
  uint32_t* Wc16 = (uint32_t*)carve((size_t)1 * GATE * HID * 2);
  const size_t WMAT = (size_t)GATE * HID / 2;   // uint32 per [1024][256] f16 matrix

  auto f2h = [&](const float* src, uint32_t* dst, int n) {
    f2h_kernel<<<(n + 255) / 256, 256, 0, stream>>>(src, (_Float16*)dst, n);
  };
  f2h(Wl_hh, Wl16, 2 * GATE * HID);
  f2h(Wh_hh, Wh16, 2 * GATE * HID);
  f2h(Wn_hh, Wn16, 4 * GATE * HID);
  f2h(Wc_hh, Wc16, 1 * GATE * HID);

  auto gemm = [&](float* C, int ldc, const float* A, int lda,
                  const float* W, int ldw, const float* bias, const float* addC,
                  int M, int N, int K) {
    dim3 g(N / 64, M / 64);
    gemm_kernel<<<g, 256, 0, stream>>>(A, lda, W, ldw, bias, addC, C, ldc, M, N, K);
  };
  auto scan3 = [&](ScanDesc a, ScanDesc b, ScanDesc c, int nblk) {
    lstm_scan2<<<nblk, 512, 0, stream>>>(a, b, c, T_LEN);
  };
  ScanDesc dummy = {};

  // ---- G0: lower Xp + node0 Xp ----
  gemm(XpA, GATE, inputs, IN_F, Wl_ih,               IN_F, bl,        nullptr, T_LEN, GATE, IN_F);
  gemm(XpB, GATE, inputs, IN_F, Wl_ih + GATE * IN_F, IN_F, bl + GATE, nullptr, T_LEN, GATE, IN_F);
  gemm(nodesA, 256, inputs, IN_F, Win, IN_F, bin_, nullptr, T_LEN, 256, IN_F);
  gather_kernel<<<T_LEN, 512, 0, stream>>>(nodesA, edges, pairb);
  gemm(ehb, 256, pairb, 512, We + (size_t)0 * HID * 512, 512, be + 0 * HID, nullptr, T_LEN, 256, 512);
  gemm(XpN, GATE, inputs, IN_F, Wn_ih + (size_t)0 * GATE * 512,       512, bn + 0 * GATE, nullptr, T_LEN, GATE, IN_F);
  gemm(XpN, GATE, ehb,    256,  Wn_ih + (size_t)0 * GATE * 512 + 256, 512, nullptr,       XpN,     T_LEN, GATE, 256);

  // ---- Slot1: lower fwd/bwd + node0 ----
  scan3({XpA, Wl16,        lower,       0, 512},
        {XpB, Wl16 + WMAT, lower + 256, 1, 512},
        {XpN, Wn16,        nodesB,      0, 256}, 3);

  // ---- G1: higher Xp + node1 Xp ----
  gemm(XpA, GATE, lower, 512, Wh_ih,              512, bh,        nullptr, T_LEN, GATE, 512);
  gemm(XpB, GATE, lower, 512, Wh_ih + GATE * 512, 512, bh + GATE, nullptr, T_LEN, GATE, 512);
  gather_kernel<<<T_LEN, 512, 0, stream>>>(nodesB, edges, pairb);
  gemm(ehb, 256, pairb, 512, We + (size_t)1 * HID * 512, 512, be + 1 * HID, nullptr, T_LEN, 256, 512);
  gemm(XpN, GATE, inputs, IN_F, Wn_ih + (size_t)1 * GATE * 512,       512, bn + 1 * GATE, nullptr, T_LEN, GATE, IN_F);
  gemm(XpN, GATE, ehb,    256,  Wn_ih + (size_t)1 * GATE * 512 + 256, 512, nullptr,       XpN,     T_LEN, GATE, 256);

  // ---- Slot2: higher fwd/bwd + node1 ----
  scan3({XpA, Wh16,        higher,       0, 512},
        {XpB, Wh16 + WMAT, higher + 256, 1, 512},
        {XpN, Wn16 + WMAT, nodesA,       0, 256}, 3);

  // ---- G2: ctrl Xp + node2 Xp ----
  gemm(XpC, GATE, inputs, IN_F, Wc_ih,       896, bc,      nullptr, T_LEN, GATE, IN_F);
  gemm(XpC, GATE, memory, 128,  Wc_ih + 768, 896, nullptr, XpC,     T_LEN, GATE, 128);
  gemm(XpC, GATE, higher, 512,  Wc_ih + 256, 896, nullptr, XpC,     T_LEN, GATE, 512);
  gather_kernel<<<T_LEN, 512, 0, stream>>>(nodesA, edges, pairb);
  gemm(ehb, 256, pairb, 512, We + (size_t)2 * HID * 512, 512, be + 2 * HID, nullptr, T_LEN, 256, 512);
  gemm(XpN, GATE, inputs, IN_F, Wn_ih + (size_t)2 * GATE * 512,       512, bn + 2 * GATE, nullptr, T_LEN, GATE, IN_F);
  gemm(XpN, GATE, ehb,    256,  Wn_ih + (size_t)2 * GATE * 512 + 256, 512, nullptr,       XpN,     T_LEN, GATE, 256);

  // ---- Slot3: node2 + ctrl ----
  scan3({XpN, Wn16 + 2 * WMAT, nodesB, 0, 256},
        {XpC, Wc16,            ctrlh,  0, 256}, dummy, 2);

  // ---- G3: node3 Xp ----
  gather_kernel<<<T_LEN, 512, 0, stream>>>(nodesB, edges, pairb);
  gemm(ehb, 256, pairb, 512, We + (size_t)3 * HID * 512, 512, be + 3 * HID, nullptr, T_LEN, 256, 512);
  gemm(XpN, GATE, inputs, IN_F, Wn_ih + (size_t)3 * GATE * 512,       512, bn + 3 * GATE, nullptr, T_LEN, GATE, IN_F);
  gemm(XpN, GATE, ehb,    256,  Wn_ih + (size_t)3 * GATE * 512 + 256, 512, nullptr,       XpN,     T_LEN, GATE, 256);

  // ---- Slot4: node3 ----
  scan3({XpN, Wn16 + 3 * WMAT, nodesA, 0, 256}, dummy, dummy, 1);

  // ---- finals ----
  gemm(memvec,  256, nodesA, 256, Wmem, HID, bmem, nullptr, T_LEN, 256, HID);
  gemm(out_ptr, 256, ctrlh,  256, Wout, HID, bout, nullptr, T_LEN, 256, HID);
}

// Round 3
// 62140.161 us; speedup vs baseline: 1.8336x; 1.0450x over previous
//
#include <hip/hip_runtime.h>
#include <cstdint>

// ---------------------------------------------------------------------------
// HierarchicalGraphMemoryNetwork on MI355X — round 3
//
// Change vs round 2: pin scan-kernel occupancy with amdgpu_waves_per_eu(2,2).
// Rounds 1/2 showed the allocator targets MORE waves than launch_bounds' min
// (VGPR_Count 64/128 = half the cap), spilling the 192-dword weight array to
// scratch -> ~13k cy/step. Forcing exactly 2 waves/SIMD gives the full 256
// VGPR budget so weights stay register-resident.
// ---------------------------------------------------------------------------

#define T_LEN 8192
#define IN_F  256
#define HID   256
#define GATE  1024
#define NREL  4
#define OUT_N 256

typedef _Float16 half2_t __attribute__((ext_vector_type(2)));

__device__ __forceinline__ float fdot2(uint32_t w, uint32_t h, float acc) {
#if __has_builtin(__builtin_amdgcn_fdot2)
  return __builtin_amdgcn_fdot2(__builtin_bit_cast(half2_t, w),
                                __builtin_bit_cast(half2_t, h), acc, false);
#else
  asm("v_dot2_f32_f16 %0, %1, %2, %0" : "+v"(acc) : "v"(w), "v"(h));
  return acc;
#endif
}

__device__ __forceinline__ float fsig(float x) { return 1.f / (1.f + __expf(-x)); }
__device__ __forceinline__ float ftanh(float x) { return 2.f / (1.f + __expf(-2.f * x)) - 1.f; }

// -------------------------- fp32 -> f16 convert ----------------------------
__global__ void f2h_kernel(const float* __restrict__ in, _Float16* __restrict__ out, int n) {
  int i = blockIdx.x * blockDim.x + threadIdx.x;
  if (i < n) out[i] = (_Float16)in[i];
}

// ------------------------------- GEMM --------------------------------------
// C[M][N] = A[M][K] * W[N][K]^T (+ bias[N]) (+ addC[M][N]); 64x64 tile/block.
__global__ __launch_bounds__(256) void gemm_kernel(
    const float* __restrict__ A, int lda,
    const float* __restrict__ W, int ldw,
    const float* __restrict__ bias,
    const float* addC,
    float* C, int ldc, int M, int N, int K) {
  __shared__ float As[16][64];
  __shared__ float Bs[16][64];
  const int tid = threadIdx.x;
  const int tx = tid & 15, ty = tid >> 4;
  const int m0 = blockIdx.y * 64, n0 = blockIdx.x * 64;
  const int lr = tid >> 2;          // 0..63
  const int lc = (tid & 3) * 4;     // 0,4,8,12
  float acc[4][4] = {};
  for (int k0 = 0; k0 < K; k0 += 16) {
    float4 av = *(const float4*)&A[(size_t)(m0 + lr) * lda + k0 + lc];
    float4 wv = *(const float4*)&W[(size_t)(n0 + lr) * ldw + k0 + lc];
    As[lc + 0][lr] = av.x; As[lc + 1][lr] = av.y; As[lc + 2][lr] = av.z; As[lc + 3][lr] = av.w;
    Bs[lc + 0][lr] = wv.x; Bs[lc + 1][lr] = wv.y; Bs[lc + 2][lr] = wv.z; Bs[lc + 3][lr] = wv.w;
    __syncthreads();
#pragma unroll
    for (int k = 0; k < 16; ++k) {
      float a[4], b[4];
#pragma unroll
      for (int i = 0; i < 4; ++i) a[i] = As[k][ty * 4 + i];
#pragma unroll
      for (int j = 0; j < 4; ++j) b[j] = Bs[k][tx * 4 + j];
#pragma unroll
      for (int i = 0; i < 4; ++i)
#pragma unroll
        for (int j = 0; j < 4; ++j) acc[i][j] += a[i] * b[j];
    }
    __syncthreads();
  }
#pragma unroll
  for (int i = 0; i < 4; ++i) {
    int m = m0 + ty * 4 + i;
#pragma unroll
    for (int j = 0; j < 4; ++j) {
      int n = n0 + tx * 4 + j;
      float v = acc[i][j];
      if (bias) v += bias[n];
      if (addC) v += addC[(size_t)m * ldc + n];
      C[(size_t)m * ldc + n] = v;
    }
  }
}

// ------------------------------ gather -------------------------------------
__global__ void gather_kernel(const float* __restrict__ nodes,
                              const int* __restrict__ edges,
                              float* __restrict__ pair) {
  int t = blockIdx.x;
  int c = threadIdx.x;              // 0..511
  int e = edges[t * 2 + (c >> 8)];
  pair[(size_t)t * 512 + c] = nodes[(size_t)e * 256 + (c & 255)];
}

// ------------------------------ LSTM scan ----------------------------------
// 512 threads, EXACTLY 2 waves/SIMD (amdgpu_waves_per_eu(2,2) -> 256 VGPR cap).
// Thread j owns gate rows j and j+512 of Whh [1024][256] f16.
// Per row: dwords 0..95 (k=0..191) in VGPR, dwords 96..127 (k=192..255) in LDS.
struct ScanDesc {
  const float* Xp;        // [T][1024] fp32 input projection (incl. bias)
  const uint32_t* W;      // [1024][128] dwords of f16 Whh
  float* out;             // h output
  int rev;                // reverse scan
  int hstride;            // out row stride
};

__global__ __launch_bounds__(512)
__attribute__((amdgpu_waves_per_eu(2, 2)))
void lstm_scan2(ScanDesc d0, ScanDesc d1, ScanDesc d2, int T) {
  ScanDesc d;
  if (blockIdx.x == 0) d = d0;
  else if (blockIdx.x == 1) d = d1;
  else d = d2;
  const float* __restrict__ Xp = d.Xp;
  const uint32_t* __restrict__ W = d.W;
  float* __restrict__ out = d.out;
  const int rev = d.rev, hstride = d.hstride;

  const int j = threadIdx.x;                 // 0..511
  __shared__ uint4 w_lds[2][8][512];         // 128 KiB (dwords 96..127 of both rows)
  __shared__ float z_lds[1024];
  __shared__ uint32_t h_lds[128];            // 256 f16

  const uint4* wrow0 = (const uint4*)(W + (size_t)j * 128);
  const uint4* wrow1 = (const uint4*)(W + (size_t)(j + 512) * 128);
  uint4 w0[24], w1[24];
#pragma unroll
  for (int q = 0; q < 24; ++q) w0[q] = wrow0[q];
#pragma unroll
  for (int q = 0; q < 24; ++q) w1[q] = wrow1[q];
#pragma unroll
  for (int q = 0; q < 8; ++q) w_lds[0][q][j] = wrow0[24 + q];
#pragma unroll
  for (int q = 0; q < 8; ++q) w_lds[1][q][j] = wrow1[24 + q];
  if (j < 128) h_lds[j] = 0u;
  float c = 0.f;
  __syncthreads();

  const int t0 = rev ? (T - 1) : 0;
  float xp0 = Xp[(size_t)t0 * GATE + j];
  float xp1 = Xp[(size_t)t0 * GATE + j + 512];

  for (int s = 0; s < T; ++s) {
    const int t = rev ? (T - 1 - s) : s;
    float a0 = xp0, a1 = 0.f, a2 = 0.f, a3 = 0.f;     // row j accumulators
    float b0 = xp1, b1 = 0.f, b2 = 0.f, b3 = 0.f;     // row j+512 accumulators
    {
      // branch-free next-step prefetch (clamped index; result unused on last step)
      int sn = (s + 1 < T) ? (s + 1) : s;
      int tn = rev ? (T - 1 - sn) : sn;
      xp0 = Xp[(size_t)tn * GATE + j];
      xp1 = Xp[(size_t)tn * GATE + j + 512];
    }

    const uint4* hq = (const uint4*)h_lds;
#pragma unroll
    for (int q = 0; q < 24; ++q) {
      uint4 hv = hq[q];
      uint4 wa = w0[q], wb = w1[q];
      a0 = fdot2(wa.x, hv.x, a0); b0 = fdot2(wb.x, hv.x, b0);
      a1 = fdot2(wa.y, hv.y, a1); b1 = fdot2(wb.y, hv.y, b1);
      a2 = fdot2(wa.z, hv.z, a2); b2 = fdot2(wb.z, hv.z, b2);
      a3 = fdot2(wa.w, hv.w, a3); b3 = fdot2(wb.w, hv.w, b3);
    }
#pragma unroll
    for (int q = 0; q < 8; ++q) {
      uint4 hv = hq[24 + q];
      uint4 wa = w_lds[0][q][j], wb = w_lds[1][q][j];
      a0 = fdot2(wa.x, hv.x, a0); b0 = fdot2(wb.x, hv.x, b0);
      a1 = fdot2(wa.y, hv.y, a1); b1 = fdot2(wb.y, hv.y, b1);
      a2 = fdot2(wa.z, hv.z, a2); b2 = fdot2(wb.z, hv.z, b2);
      a3 = fdot2(wa.w, hv.w, a3); b3 = fdot2(wb.w, hv.w, b3);
    }
    z_lds[j] = (a0 + a1) + (a2 + a3);
    z_lds[j + 512] = (b0 + b1) + (b2 + b3);
    __syncthreads();

    if (j < HID) {
      float zi = z_lds[j], zf = z_lds[j + 256], zg = z_lds[j + 512], zo = z_lds[j + 768];
      float ig = fsig(zi), fg = fsig(zf), gg = ftanh(zg), og = fsig(zo);
      c = fg * c + ig * gg;
      float h = og * ftanh(c);
      out[(size_t)t * hstride + j] = h;
      ((_Float16*)h_lds)[j] = (_Float16)h;
    }
    __syncthreads();
  }
}

// ---------------------------------------------------------------------------
extern "C" void kernel_launch(void* const* d_in, const int* in_sizes, int n_in,
                              void* d_out, int out_size, void* d_ws, size_t ws_size,
                              hipStream_t stream) {
  (void)in_sizes; (void)n_in; (void)out_size; (void)ws_size;
  const float* inputs = (const float*)d_in[0];
  const int*   edges  = (const int*)d_in[1];
  const float* memory = (const float*)d_in[2];
  const float* Wl_ih  = (const float*)d_in[3];
  const float* Wl_hh  = (const float*)d_in[4];
  const float* bl     = (const float*)d_in[5];
  const float* Wh_ih  = (const float*)d_in[6];
  const float* Wh_hh  = (const float*)d_in[7];
  const float* bh     = (const float*)d_in[8];
  const float* Win    = (const float*)d_in[9];
  const float* bin_   = (const float*)d_in[10];
  const float* We     = (const float*)d_in[11];
  const float* be     = (const float*)d_in[12];
  const float* Wn_ih  = (const float*)d_in[13];
  const float* Wn_hh  = (const float*)d_in[14];
  const float* bn     = (const float*)d_in[15];
  const float* Wmem   = (const float*)d_in[16];
  const float* bmem   = (const float*)d_in[17];
  const float* Wc_ih  = (const float*)d_in[18];
  const float* Wc_hh  = (const float*)d_in[19];
  const float* bc     = (const float*)d_in[20];
  const float* Wout   = (const float*)d_in[21];
  const float* bout   = (const float*)d_in[22];

  float* out_ptr = (float*)d_out;                       // [T][256]
  float* memvec  = out_ptr + (size_t)T_LEN * OUT_N;     // [T][256]

  // ---- workspace carve ----
  char* base = (char*)d_ws;
  size_t off = 0;
  auto carve = [&](size_t nbytes) -> void* {
    void* p = base + off; off += (nbytes + 255) & ~(size_t)255; return p;
  };
  float* XpA    = (float*)carve((size_t)T_LEN * GATE * 4);
  float* XpB    = (float*)carve((size_t)T_LEN * GATE * 4);
  float* XpC    = (float*)carve((size_t)T_LEN * GATE * 4);
  float* XpN    = (float*)carve((size_t)T_LEN * GATE * 4);
  float* lower  = (float*)carve((size_t)T_LEN * 512 * 4);
  float* higher = (float*)carve((size_t)T_LEN * 512 * 4);
  float* nodesA = (float*)carve((size_t)T_LEN * 256 * 4);
  float* nodesB = (float*)carve((size_t)T_LEN * 256 * 4);
  float* pairb  = (float*)carve((size_t)T_LEN * 512 * 4);
  float* ehb    = (float*)carve((size_t)T_LEN * 256 * 4);
  float* ctrlh  = (float*)carve((size_t)T_LEN * 256 * 4);
  uint32_t* Wl16 = (uint32_t*)carve((size_t)2 * GATE * HID * 2);
  uint32_t* Wh16 = (uint32_t*)carve((size_t)2 * GATE * HID * 2);
  uint32_t* Wn16 = (uint32_t*)carve((size_t)4 * GATE * HID * 2);
  uint32_t* Wc16 = (uint32_t*)carve((size_t)1 * GATE * HID * 2);
  const size_t WMAT = (size_t)GATE * HID / 2;   // uint32 per [1024][256] f16 matrix

  auto f2h = [&](const float* src, uint32_t* dst, int n) {
    f2h_kernel<<<(n + 255) / 256, 256, 0, stream>>>(src, (_Float16*)dst, n);
  };
  f2h(Wl_hh, Wl16, 2 * GATE * HID);
  f2h(Wh_hh, Wh16, 2 * GATE * HID);
  f2h(Wn_hh, Wn16, 4 * GATE * HID);
  f2h(Wc_hh, Wc16, 1 * GATE * HID);

  auto gemm = [&](float* C, int ldc, const float* A, int lda,
                  const float* W, int ldw, const float* bias, const float* addC,
                  int M, int N, int K) {
    dim3 g(N / 64, M / 64);
    gemm_kernel<<<g, 256, 0, stream>>>(A, lda, W, ldw, bias, addC, C, ldc, M, N, K);
  };
  auto scan3 = [&](ScanDesc a, ScanDesc b, ScanDesc c, int nblk) {
    lstm_scan2<<<nblk, 512, 0, stream>>>(a, b, c, T_LEN);
  };
  ScanDesc dummy = {};

  // ---- G0: lower Xp + node0 Xp ----
  gemm(XpA, GATE, inputs, IN_F, Wl_ih,               IN_F, bl,        nullptr, T_LEN, GATE, IN_F);
  gemm(XpB, GATE, inputs, IN_F, Wl_ih + GATE * IN_F, IN_F, bl + GATE, nullptr, T_LEN, GATE, IN_F);
  gemm(nodesA, 256, inputs, IN_F, Win, IN_F, bin_, nullptr, T_LEN, 256, IN_F);
  gather_kernel<<<T_LEN, 512, 0, stream>>>(nodesA, edges, pairb);
  gemm(ehb, 256, pairb, 512, We + (size_t)0 * HID * 512, 512, be + 0 * HID, nullptr, T_LEN, 256, 512);
  gemm(XpN, GATE, inputs, IN_F, Wn_ih + (size_t)0 * GATE * 512,       512, bn + 0 * GATE, nullptr, T_LEN, GATE, IN_F);
  gemm(XpN, GATE, ehb,    256,  Wn_ih + (size_t)0 * GATE * 512 + 256, 512, nullptr,       XpN,     T_LEN, GATE, 256);

  // ---- Slot1: lower fwd/bwd + node0 ----
  scan3({XpA, Wl16,        lower,       0, 512},
        {XpB, Wl16 + WMAT, lower + 256, 1, 512},
        {XpN, Wn16,        nodesB,      0, 256}, 3);

  // ---- G1: higher Xp + node1 Xp ----
  gemm(XpA, GATE, lower, 512, Wh_ih,              512, bh,        nullptr, T_LEN, GATE, 512);
  gemm(XpB, GATE, lower, 512, Wh_ih + GATE * 512, 512, bh + GATE, nullptr, T_LEN, GATE, 512);
  gather_kernel<<<T_LEN, 512, 0, stream>>>(nodesB, edges, pairb);
  gemm(ehb, 256, pairb, 512, We + (size_t)1 * HID * 512, 512, be + 1 * HID, nullptr, T_LEN, 256, 512);
  gemm(XpN, GATE, inputs, IN_F, Wn_ih + (size_t)1 * GATE * 512,       512, bn + 1 * GATE, nullptr, T_LEN, GATE, IN_F);
  gemm(XpN, GATE, ehb,    256,  Wn_ih + (size_t)1 * GATE * 512 + 256, 512, nullptr,       XpN,     T_LEN, GATE, 256);

  // ---- Slot2: higher fwd/bwd + node1 ----
  scan3({XpA, Wh16,        higher,       0, 512},
        {XpB, Wh16 + WMAT, higher + 256, 1, 512},
        {XpN, Wn16 + WMAT, nodesA,       0, 256}, 3);

  // ---- G2: ctrl Xp + node2 Xp ----
  gemm(XpC, GATE, inputs, IN_F, Wc_ih,       896, bc,      nullptr, T_LEN, GATE, IN_F);
  gemm(XpC, GATE, memory, 128,  Wc_ih + 768, 896, nullptr, XpC,     T_LEN, GATE, 128);
  gemm(XpC, GATE, higher, 512,  Wc_ih + 256, 896, nullptr, XpC,     T_LEN, GATE, 512);
  gather_kernel<<<T_LEN, 512, 0, stream>>>(nodesA, edges, pairb);
  gemm(ehb, 256, pairb, 512, We + (size_t)2 * HID * 512, 512, be + 2 * HID, nullptr, T_LEN, 256, 512);
  gemm(XpN, GATE, inputs, IN_F, Wn_ih + (size_t)2 * GATE * 512,       512, bn + 2 * GATE, nullptr, T_LEN, GATE, IN_F);
  gemm(XpN, GATE, ehb,    256,  Wn_ih + (size_t)2 * GATE * 512 + 256, 512, nullptr,       XpN,     T_LEN, GATE, 256);

  // ---- Slot3: node2 + ctrl ----
  scan3({XpN, Wn16 + 2 * WMAT, nodesB, 0, 256},
        {XpC, Wc16,            ctrlh,  0, 256}, dummy, 2);

  // ---- G3: node3 Xp ----
  gather_kernel<<<T_LEN, 512, 0, stream>>>(nodesB, edges, pairb);
  gemm(ehb, 256, pairb, 512, We + (size_t)3 * HID * 512, 512, be + 3 * HID, nullptr, T_LEN, 256, 512);
  gemm(XpN, GATE, inputs, IN_F, Wn_ih + (size_t)3 * GATE * 512,       512, bn + 3 * GATE, nullptr, T_LEN, GATE, IN_F);
  gemm(XpN, GATE, ehb,    256,  Wn_ih + (size_t)3 * GATE * 512 + 256, 512, nullptr,       XpN,     T_LEN, GATE, 256);

  // ---- Slot4: node3 ----
  scan3({XpN, Wn16 + 3 * WMAT, nodesA, 0, 256}, dummy, dummy, 1);

  // ---- finals ----
  gemm(memvec,  256, nodesA, 256, Wmem, HID, bmem, nullptr, T_LEN, 256, HID);
  gemm(out_ptr, 256, ctrlh,  256, Wout, HID, bout, nullptr, T_LEN, 256, HID);
}